// Round 18
// baseline (433.933 us; speedup 1.0000x reference)
//
#include <hip/hip_runtime.h>

typedef unsigned short u16;
typedef unsigned int u32;
typedef __attribute__((ext_vector_type(8))) short bf16x8;
typedef __attribute__((ext_vector_type(8))) u16  u16x8;
typedef __attribute__((ext_vector_type(4))) float f32x4;

#define TOK   33048      // B*J*N = 8*17*243
#define NSEQ  243
#define TE    16920576u  // elems per blocked Q/K tensor: 1088*243*64
#define GSTR  15552      // 243*64
#define VTP   256        // padded n-stride of V^T (16384 elems per g)

__device__ __forceinline__ float bf2f(u16 u){
    union { unsigned int i; float f; } v; v.i = ((unsigned int)u) << 16; return v.f;
}
__device__ __forceinline__ u16 f2bf(float f){
    union { float f; unsigned int i; } v; v.f = f;
    unsigned int r = v.i + 0x7fffu + ((v.i >> 16) & 1u);
    return (u16)(r >> 16);
}

__device__ __forceinline__ void gload_lds16(const void* g, void* l){
    __builtin_amdgcn_global_load_lds(
        (const __attribute__((address_space(1))) unsigned int*)g,
        (__attribute__((address_space(3))) unsigned int*)l, 16, 0, 0);
}

// ---------------- x -> token-major bf16 ----------------
__global__ __launch_bounds__(256) void k_cvt_xbf(const float* __restrict__ x, u16* __restrict__ xbf){
    int idx = blockIdx.x*256 + threadIdx.x;
    int t  = idx >> 6;
    int c8 = (idx & 63) << 3;
    unsigned b   = (unsigned)t / 4131u;
    unsigned rem = (unsigned)t % 4131u;
    unsigned j = rem / 243u, n = rem % 243u;
    const float* src = x + ((size_t)(b*243u + n)*17u + j)*512u + c8;
    f32x4 a = *(const f32x4*)src;
    f32x4 c = *(const f32x4*)(src+4);
    u16x8 o;
    #pragma unroll
    for (int e=0;e<4;e++){ o[e]=f2bf(a[e]); o[e+4]=f2bf(c[e]); }
    *(u16x8*)(xbf + (size_t)t*512 + c8) = o;
}

// ---------------- weight conversions ----------------
__global__ __launch_bounds__(256) void k_cvt_wcat(const float* __restrict__ Wqkv,
                                                  const float* __restrict__ Wq,
                                                  const float* __restrict__ Wkv,
                                                  u16* __restrict__ WcatT){
    int idx = blockIdx.x*256 + threadIdx.x;
    int k  = idx / 384;
    int c0 = (idx % 384) * 8;
    const float* src;
    if (c0 < 1536)      src = Wqkv + (size_t)k*1536 + c0;
    else if (c0 < 2048) src = Wq   + (size_t)k*512  + (c0 - 1536);
    else                src = Wkv  + (size_t)k*1024 + (c0 - 2048);
    f32x4 a = *(const f32x4*)src;
    f32x4 b = *(const f32x4*)(src+4);
    #pragma unroll
    for (int e=0;e<4;e++){
        WcatT[(size_t)(c0+e)*512 + k]   = f2bf(a[e]);
        WcatT[(size_t)(c0+4+e)*512 + k] = f2bf(b[e]);
    }
}

__global__ __launch_bounds__(256) void k_cvt_wproj(const float* __restrict__ Wp, u16* __restrict__ WpT){
    int idx = blockIdx.x*256 + threadIdx.x;
    int k  = idx / 64;
    int c0 = (idx % 64) * 8;
    f32x4 a = *(const f32x4*)(Wp + (size_t)k*512 + c0);
    f32x4 b = *(const f32x4*)(Wp + (size_t)k*512 + c0 + 4);
    #pragma unroll
    for (int e=0;e<4;e++){
        WpT[(size_t)(c0+e)*512 + k]   = f2bf(a[e]);
        WpT[(size_t)(c0+4+e)*512 + k] = f2bf(b[e]);
    }
}

// ---------------- input GEMM  M=33048 x N=1536(half) x K=512 ----------------
// 128x256 tile, BK=64, single 48KB LDS (A 16KB + B 32KB), 2-barrier m97 loop,
// XOR-swizzled both-sides. Wave tile 64x128 (acc 4x8).
// writes blocked Q (pre-scaled 1/8) @0, K @TE, V^T @2*TE
__global__ __launch_bounds__(256) void k_gemm_in(
    const u16* __restrict__ xbf, const u16* __restrict__ WcatT,
    const float* __restrict__ b_qkv, const float* __restrict__ b_q,
    const float* __restrict__ b_kv, u16* __restrict__ ws3, int c_off)
{
    __shared__ __align__(16) u16 smem[24576];   // 48KB: A [128][64] @0, B [256][64] @8192

    // bijective XCD swizzle over 1554 blocks (q=194, r=2)
    const int orig = blockIdx.x;
    const int xcd  = orig & 7;
    const int wg   = (xcd < 2 ? xcd*195 : 2*195 + (xcd-2)*194) + (orig >> 3);
    const int nt = wg % 6, mt = wg / 6;

    const int tid = threadIdx.x;
    const int w = tid >> 6, lane = tid & 63;
    const int wm = w >> 1, wn = w & 1;
    const int lg = lane >> 4, li = lane & 15;
    const int x7 = li & 7;

    const int sr8  = lane >> 3;
    const int schx = (lane & 7) ^ sr8;
    const u16* gA = xbf   + (size_t)(mt*128 + w*32 + sr8)*512 + schx*8;
    const u16* gB = WcatT + (size_t)(c_off + nt*256 + w*64 + sr8)*512 + schx*8;

    f32x4 acc[4][8];
    #pragma unroll
    for (int i=0;i<4;i++)
        #pragma unroll
        for (int jj=0;jj<8;jj++){ acc[i][jj][0]=0.f; acc[i][jj][1]=0.f; acc[i][jj][2]=0.f; acc[i][jj][3]=0.f; }

    #pragma unroll
    for (int k0 = 0; k0 < 512; k0 += 64){
        __syncthreads();                      // prior compute's LDS reads done
        #pragma unroll
        for (int i=0;i<4;i++)
            gload_lds16(gA + i*4096 + k0, smem + (w*32 + i*8)*64);
        #pragma unroll
        for (int i=0;i<8;i++)
            gload_lds16(gB + i*4096 + k0, smem + 8192 + (w*64 + i*8)*64);
        __syncthreads();                      // staged tile visible (vmcnt drained)
        const u16* As = smem;
        const u16* Bs = smem + 8192;
        #pragma unroll
        for (int ks=0; ks<2; ks++){
            bf16x8 av[4], bv[8];
            #pragma unroll
            for (int mf=0;mf<4;mf++){
                const int R = wm*64 + mf*16 + li;
                av[mf] = *(const bf16x8*)&As[R*64 + (((ks*4+lg) ^ x7)*8)];
            }
            #pragma unroll
            for (int nf=0;nf<8;nf++){
                const int R = wn*128 + nf*16 + li;
                bv[nf] = *(const bf16x8*)&Bs[R*64 + (((ks*4+lg) ^ x7)*8)];
            }
            #pragma unroll
            for (int mf=0;mf<4;mf++)
                #pragma unroll
                for (int nf=0;nf<8;nf++)
                    acc[mf][nf] = __builtin_amdgcn_mfma_f32_16x16x32_bf16(av[mf], bv[nf], acc[mf][nf], 0, 0, 0);
        }
    }

    float bias[8];
    #pragma unroll
    for (int nf=0;nf<8;nf++){
        const int c = c_off + nt*256 + wn*128 + nf*16 + li;
        bias[nf] = (c < 1536) ? b_qkv[c] : (c < 2048 ? b_q[c-1536] : b_kv[c-2048]);
    }

    // epilogue: two 64-col halves, each via per-wave 16x72 LDS tile -> blocked stores
    u16* L = smem + w*1152;
    const int rloc = lane & 15;
    const int cchunk = lane >> 4;
    u16* vt = ws3 + (size_t)2 * TE;

    #pragma unroll
    for (int nfh=0; nfh<2; nfh++){
        const int colbase = nt*256 + wn*128 + nfh*64;   // multiple of 64
        const int slot = colbase >> 9;                  // 0=Q,1=K,2=V
        const float osc = (slot == 0) ? 0.125f : 1.0f;
        const int hh   = (colbase >> 6) & 7;
        const int dd = (colbase + cchunk*8) & 63;
        u16* tbase = ws3 + (size_t)slot * TE;

        #pragma unroll
        for (int mf=0;mf<4;mf++){
            __syncthreads();
            #pragma unroll
            for (int nf=0;nf<4;nf++)
                #pragma unroll
                for (int reg=0;reg<4;reg++)
                    L[(lg*4+reg)*72 + nf*16 + li] = f2bf((acc[mf][nfh*4+nf][reg] + bias[nfh*4+nf]) * osc);
            __syncthreads();
            const int rr_base = mt*128 + wm*64 + mf*16;
            if (slot < 2){
                const int rr = rr_base + rloc;
                if (rr < TOK){
                    u16x8 v0 = *(const u16x8*)&L[rloc*72 + cchunk*8];
                    u16x8 v1 = *(const u16x8*)&L[rloc*72 + 32 + cchunk*8];
                    const unsigned bj = (unsigned)rr / 243u;
                    const unsigned n  = (unsigned)rr % 243u;
                    u16* dst = tbase + ((size_t)(bj*8u + hh)*243u + n)*64u + dd;
                    *(u16x8*)dst      = v0;
                    *(u16x8*)(dst+32) = v1;
                }
            } else {
                u16 colv[16];
                #pragma unroll
                for (int r=0;r<16;r++) colv[r] = L[r*72 + lane];
                if (rr_base < TOK){
                    const unsigned bj0 = (unsigned)rr_base / 243u;
                    const unsigned n0  = (unsigned)rr_base % 243u;
                    if (n0 <= 227 && rr_base + 15 < TOK){
                        u16x8 vlo, vhi;
                        #pragma unroll
                        for (int e=0;e<8;e++){ vlo[e]=colv[e]; vhi[e]=colv[e+8]; }
                        u16* dst = vt + ((size_t)(bj0*8u + hh)*64u + lane)*VTP + n0;
                        *(u16x8*)dst     = vlo;
                        *(u16x8*)(dst+8) = vhi;
                    } else {
                        for (int r=0;r<16;r++){
                            const int rr = rr_base + r;
                            if (rr < TOK){
                                const unsigned bjr = (unsigned)rr / 243u;
                                const unsigned nr  = (unsigned)rr % 243u;
                                vt[((size_t)(bjr*8u + hh)*64u + lane)*VTP + nr] = colv[r];
                            }
                        }
                    }
                }
            }
        }
    }
}

// ---------------- child-mean pre-mix kernels ----------------
__constant__ int g_child[17][3] = {
  {1,4,7},{2,-1,-1},{3,-1,-1},{3,-1,-1},{5,-1,-1},{6,-1,-1},{6,-1,-1},{8,-1,-1},
  {9,11,14},{10,-1,-1},{10,-1,-1},{12,-1,-1},{13,-1,-1},{13,-1,-1},{15,-1,-1},
  {16,-1,-1},{16,-1,-1}};
__constant__ float g_cw[17] = {0.33333333f,1,1,1,1,1,1,1,0.33333333f,1,1,1,1,1,1,1,1};

__global__ __launch_bounds__(256) void k_mixk(const u16* __restrict__ Kraw, u16* __restrict__ Kmix){
    const int c = blockIdx.x*256 + threadIdx.x;    // 2,115,072 = 1088*1944
    const int g = c / 1944;
    const int off = (c % 1944) * 8;
    const int bj = g >> 3, h = g & 7;
    const int b_ = bj / 17, j_ = bj % 17;
    const float wgt = g_cw[j_];
    float acc[8];
    #pragma unroll
    for (int e=0;e<8;e++) acc[e]=0.f;
    #pragma unroll
    for (int ci=0;ci<3;ci++){
        const int cj = g_child[j_][ci];
        if (cj >= 0){
            const u16x8 v = *(const u16x8*)(Kraw + (size_t)((b_*17+cj)*8+h)*GSTR + off);
            #pragma unroll
            for (int e=0;e<8;e++) acc[e] += wgt*bf2f(v[e]);
        }
    }
    u16x8 o;
    #pragma unroll
    for (int e=0;e<8;e++) o[e]=f2bf(acc[e]);
    *(u16x8*)(Kmix + (size_t)g*GSTR + off) = o;
}

__global__ __launch_bounds__(256) void k_mixv(const u16* __restrict__ VTraw, u16* __restrict__ VTmix){
    const int c = blockIdx.x*256 + threadIdx.x;    // 2,228,224 = 1088*2048
    const int g = c / 2048;
    const int off = (c % 2048) * 8;
    const int bj = g >> 3, h = g & 7;
    const int b_ = bj / 17, j_ = bj % 17;
    const float wgt = g_cw[j_];
    float acc[8];
    #pragma unroll
    for (int e=0;e<8;e++) acc[e]=0.f;
    #pragma unroll
    for (int ci=0;ci<3;ci++){
        const int cj = g_child[j_][ci];
        if (cj >= 0){
            const u16x8 v = *(const u16x8*)(VTraw + (size_t)((b_*17+cj)*8+h)*16384u + off);
            #pragma unroll
            for (int e=0;e<8;e++) acc[e] += wgt*bf2f(v[e]);
        }
    }
    u16x8 o;
    #pragma unroll
    for (int e=0;e<8;e++) o[e]=f2bf(acc[e]);
    *(u16x8*)(VTmix + (size_t)g*16384u + off) = o;
}

// ---------------- fused attention: flash-style, async staging, counted vmcnt dbuf ------
__global__ __launch_bounds__(256, 3) void k_attn(
    const u16* __restrict__ Qb, const u16* __restrict__ Kb,
    const u16* __restrict__ VTb, u16* __restrict__ attn, int rmw)
{
    __shared__ __align__(16) u16 smem[16384];      // 32KB

    // XCD-grouping swizzle: both halves of a g land on one XCD
    const int orig = blockIdx.x;                   // 2176
    const int xcd  = orig & 7;
    const int lin  = orig >> 3;
    const int p2   = lin & 1;
    const int g    = (lin >> 1)*8 + xcd;
    const int bj = g >> 3, h = g & 7;

    const int tid = threadIdx.x, lane = tid & 63, w = tid >> 6;
    const int lg = lane >> 4, li = lane & 15;

    // Q (pre-scaled by 1/8 at GEMM)
    const int qrowA = p2*128 + w*16;
    const int qrowB = qrowA + 64;
    bf16x8 qA0 = {0,0,0,0,0,0,0,0}, qA1 = qA0, qB0 = qA0, qB1 = qA0;
    {
        const int qrA = qrowA + li;
        const u16* qp = Qb + (size_t)g*GSTR + (size_t)qrA*64;
        qA0 = *(const bf16x8*)(qp + lg*8);
        qA1 = *(const bf16x8*)(qp + 32 + lg*8);
        const int qrB = qrowB + li;
        if (qrB < NSEQ){
            const u16* qp2 = Qb + (size_t)g*GSTR + (size_t)qrB*64;
            qB0 = *(const bf16x8*)(qp2 + lg*8);
            qB1 = *(const bf16x8*)(qp2 + 32 + lg*8);
        }
    }

    // staging source (inverse-swizzled): lane l covers row (l>>3), chunk (l&7)^(l>>3)
    const int schx = (lane & 7) ^ (lane >> 3);
    const u16* ksrc = Kb  + (size_t)g*GSTR   + (size_t)(w*16 + (lane>>3))*64  + schx*8;
    const u16* vsrc = VTb + (size_t)g*16384u + (size_t)(w*16 + (lane>>3))*VTP + schx*8;

    const int laneA = li + 32*(lg & 1);
    const int laneB = laneA + 16;
    const bool sel = (lg >> 1) != 0;
    const int x7 = li & 7;

    float sumA = 0.f, sumB = 0.f;
    f32x4 oA[4], oB[4];
    #pragma unroll
    for (int dn=0;dn<4;dn++){
        oA[dn][0]=0.f; oA[dn][1]=0.f; oA[dn][2]=0.f; oA[dn][3]=0.f;
        oB[dn][0]=0.f; oB[dn][1]=0.f; oB[dn][2]=0.f; oB[dn][3]=0.f;
    }

    // prologue: stage t=0 into buffer 0 (4 loads in flight)
    {
        char* b0 = (char*)smem;
        gload_lds16(ksrc,         b0 + w*2048);
        gload_lds16(ksrc + 512,   b0 + w*2048 + 1024);
        gload_lds16(vsrc,         b0 + 8192 + w*2048);
        gload_lds16(vsrc + 8*VTP, b0 + 8192 + w*2048 + 1024);
    }

    int cur = 0;
    #pragma unroll
    for (int t=0; t<4; t++){
        if (t < 3){
            char* nb = (char*)smem + (cur^1)*16384;
            gload_lds16(ksrc + (size_t)(t+1)*4096,        nb + w*2048);
            gload_lds16(ksrc + (size_t)(t+1)*4096 + 512,  nb + w*2048 + 1024);
            gload_lds16(vsrc + (t+1)*64,                  nb + 8192 + w*2048);
            gload_lds16(vsrc + (t+1)*64 + 8*VTP,          nb + 8192 + w*2048 + 1024);
            asm volatile("s_waitcnt vmcnt(4)");   // tile t landed; t+1 stays in flight
        } else {
            asm volatile("s_waitcnt vmcnt(0)");
        }
        __builtin_amdgcn_s_barrier();
        char* kl = (char*)smem + cur*16384;
        char* vl = kl + 8192;

        #pragma unroll
        for (int half=0; half<2; half++){
            u32 lo2A[2], hi2A[2], lo2B[2], hi2B[2];
            #pragma unroll
            for (int t2=0; t2<2; t2++){
                const int nt2l = half*2 + t2;       // 0..3
                const int row  = nt2l*16 + li;      // local K row
                const bf16x8 kb0 = *(const bf16x8*)(kl + row*128 + (((lg  ) ^ x7)<<4));
                const bf16x8 kb1 = *(const bf16x8*)(kl + row*128 + (((4+lg) ^ x7)<<4));
                f32x4 sA; sA[0]=0.f; sA[1]=0.f; sA[2]=0.f; sA[3]=0.f;
                f32x4 sB = sA;
                sA = __builtin_amdgcn_mfma_f32_16x16x32_bf16(kb0, qA0, sA, 0,0,0);
                sA = __builtin_amdgcn_mfma_f32_16x16x32_bf16(kb1, qA1, sA, 0,0,0);
                sB = __builtin_amdgcn_mfma_f32_16x16x32_bf16(kb0, qB0, sB, 0,0,0);
                sB = __builtin_amdgcn_mfma_f32_16x16x32_bf16(kb1, qB1, sB, 0,0,0);
                if (t == 3 && nt2l == 3){           // k = 240 + lg*4 + r >= 243
                    sA[3] = -1e30f; sB[3] = -1e30f;
                    if (lg){ sA[0]=-1e30f; sA[1]=-1e30f; sA[2]=-1e30f;
                             sB[0]=-1e30f; sB[1]=-1e30f; sB[2]=-1e30f; }
                }
                const float a0 = __expf(sA[0]);
                const float a1 = __expf(sA[1]);
                const float a2 = __expf(sA[2]);
                const float a3 = __expf(sA[3]);
                sumA += (a0+a1)+(a2+a3);
                lo2A[t2] = (u32)f2bf(a0) | ((u32)f2bf(a1) << 16);
                hi2A[t2] = (u32)f2bf(a2) | ((u32)f2bf(a3) << 16);
                const float b0 = __expf(sB[0]);
                const float b1 = __expf(sB[1]);
                const float b2 = __expf(sB[2]);
                const float b3 = __expf(sB[3]);
                sumB += (b0+b1)+(b2+b3);
                lo2B[t2] = (u32)f2bf(b0) | ((u32)f2bf(b1) << 16);
                hi2B[t2] = (u32)f2bf(b2) | ((u32)f2bf(b3) << 16);
            }
            // shuffle -> PV A-fragments: pa elem e = P[q=li][k=kt*32+lg*8+e]
            bf16x8 paA, paB;
            {
                u32 a0 = __shfl((int)lo2A[0], laneA), a1 = __shfl((int)lo2A[1], laneA);
                u32 b0 = __shfl((int)hi2A[0], laneA), b1 = __shfl((int)hi2A[1], laneA);
                u32 c0 = __shfl((int)lo2A[0], laneB), c1 = __shfl((int)lo2A[1], laneB);
                u32 d0 = __shfl((int)hi2A[0], laneB), d1 = __shfl((int)hi2A[1], laneB);
                union { u32 u[4]; bf16x8 v; } pk;
                pk.u[0] = sel ? a1 : a0;
                pk.u[1] = sel ? b1 : b0;
                pk.u[2] = sel ? c1 : c0;
                pk.u[3] = sel ? d1 : d0;
                paA = pk.v;
            }
            {
                u32 a0 = __shfl((int)lo2B[0], laneA), a1 = __shfl((int)lo2B[1], laneA);
                u32 b0 = __shfl((int)hi2B[0], laneA), b1 = __shfl((int)hi2B[1], laneA);
                u32 c0 = __shfl((int)lo2B[0], laneB), c1 = __shfl((int)lo2B[1], laneB);
                u32 d0 = __shfl((int)hi2B[0], laneB), d1 = __shfl((int)hi2B[1], laneB);
                union { u32 u[4]; bf16x8 v; } pk;
                pk.u[0] = sel ? a1 : a0;
                pk.u[1] = sel ? b1 : b0;
                pk.u[2] = sel ? c1 : c0;
                pk.u[3] = sel ? d1 : d0;
                paB = pk.v;
            }
            #pragma unroll
            for (int dn=0;dn<4;dn++){
                const int d = dn*16 + li;
                const bf16x8 vb = *(const bf16x8*)(vl + d*128 + ((((half<<2)+lg) ^ x7)<<4));
                oA[dn] = __builtin_amdgcn_mfma_f32_16x16x32_bf16(paA, vb, oA[dn], 0,0,0);
                oB[dn] = __builtin_amdgcn_mfma_f32_16x16x32_bf16(paB, vb, oB[dn], 0,0,0);
            }
        }
        __builtin_amdgcn_s_barrier();    // all reads of buf[cur] done before overwrite
        cur ^= 1;
    }

    sumA += __shfl_xor(sumA,16); sumA += __shfl_xor(sumA,32);
    sumB += __shfl_xor(sumB,16); sumB += __shfl_xor(sumB,32);
    const float invA = 1.f/sumA;
    const float invB = 1.f/sumB;
    float invrA[4], invrB[4];
    #pragma unroll
    for (int r=0;r<4;r++){
        invrA[r] = __shfl(invA, lg*4+r);
        invrB[r] = __shfl(invB, lg*4+r);
    }

    #pragma unroll
    for (int dn=0;dn<4;dn++){
        #pragma unroll
        for (int r=0;r<4;r++){
            const int qrow = qrowA + lg*4 + r;
            const size_t off = ((size_t)bj*243 + qrow)*512 + h*64 + dn*16 + li;
            float val = oA[dn][r] * invrA[r];
            if (rmw) val += bf2f(attn[off]);
            attn[off] = f2bf(val);
        }
        #pragma unroll
        for (int r=0;r<4;r++){
            const int qrow = qrowB + lg*4 + r;
            if (qrow < NSEQ){
                const size_t off = ((size_t)bj*243 + qrow)*512 + h*64 + dn*16 + li;
                float val = oB[dn][r] * invrB[r];
                if (rmw) val += bf2f(attn[off]);
                attn[off] = f2bf(val);
            }
        }
    }
}

// ---------------- projection GEMM  M=33048 x N=512 x K=512 -> bf16 fuse ----------------
// BK=64, single 32KB LDS (m97 structure), XOR-swizzled.
__global__ __launch_bounds__(256) void k_gemm_proj(
    const u16* __restrict__ attnb, const u16* __restrict__ WprojT,
    const float* __restrict__ b_proj, u16* __restrict__ fuseb)
{
    __shared__ __align__(16) u16 smem[16384];   // 32KB: A 16KB @0, B 16KB @8192

    const int orig = blockIdx.x;
    const int xcd  = orig & 7;
    const int wg   = (xcd < 4 ? xcd*130 : 4*130 + (xcd-4)*129) + (orig >> 3);
    const int nt = wg & 3, mt = wg >> 2;

    const int tid = threadIdx.x;
    const int w = tid >> 6, lane = tid & 63;
    const int wm = w >> 1, wn = w & 1;
    const int lg = lane >> 4, li = lane & 15;
    const int x7 = li & 7;

    const int sr8  = lane >> 3;
    const int schx = (lane & 7) ^ sr8;
    const u16* gA = attnb  + (size_t)(mt*128 + w*32 + sr8)*512 + schx*8;
    const u16* gB = WprojT + (size_t)(nt*128 + w*32 + sr8)*512 + schx*8;

    f32x4 acc[4][4];
    #pragma unroll
    for (int i=0;i<4;i++)
        #pragma unroll
        for (int jj=0;jj<4;jj++){ acc[i][jj][0]=0.f; acc[i][jj][1]=0.f; acc[i][jj][2]=0.f; acc[i][jj][3]=0.f; }

    #pragma unroll
    for (int k0 = 0; k0 < 512; k0 += 64){
        __syncthreads();
        #pragma unroll
        for (int i=0;i<4;i++){
            gload_lds16(gA + i*4096 + k0, smem + (w*32 + i*8)*64);
            gload_lds16(gB + i*4096 + k0, smem + 8192 + (w*32 + i*8)*64);
        }
        __syncthreads();
        const u16* As = smem;
        const u16* Bs = smem + 8192;
        #pragma unroll
        for (int ks=0; ks<2; ks++){
            bf16x8 av[4], bv[4];
            #pragma unroll
            for (int mf=0;mf<4;mf++){
                const int R = wm*64 + mf*16 + li;
                av[mf] = *(const bf16x8*)&As[R*64 + (((ks*4+lg) ^ x7)*8)];
            }
            #pragma unroll
            for (int nf=0;nf<4;nf++){
                const int R = wn*64 + nf*16 + li;
                bv[nf] = *(const bf16x8*)&Bs[R*64 + (((ks*4+lg) ^ x7)*8)];
            }
            #pragma unroll
            for (int mf=0;mf<4;mf++)
                #pragma unroll
                for (int nf=0;nf<4;nf++)
                    acc[mf][nf] = __builtin_amdgcn_mfma_f32_16x16x32_bf16(av[mf], bv[nf], acc[mf][nf], 0, 0, 0);
        }
    }

    #pragma unroll
    for (int mf=0;mf<4;mf++)
        #pragma unroll
        for (int reg=0;reg<4;reg++){
            const int rr = mt*128 + wm*64 + mf*16 + lg*4 + reg;
            if (rr < TOK){
                #pragma unroll
                for (int nf=0;nf<4;nf++){
                    const int c = nt*128 + wn*64 + nf*16 + li;
                    fuseb[(size_t)rr*512 + c] = f2bf(acc[mf][nf][reg] + b_proj[c]);
                }
            }
        }
}

// ---------------- residual + LayerNorm (bf16 fuse, (b,j,n)->(b,n,j) permute) ------------
__global__ __launch_bounds__(256) void k_ln(
    const float* __restrict__ x, const u16* __restrict__ fuseb, float* __restrict__ out)
{
    const int w = threadIdx.x >> 6, lane = threadIdx.x & 63;
    const int o = blockIdx.x*4 + w;
    const unsigned b_  = (unsigned)o / 4131u;
    const unsigned rem = (unsigned)o % 4131u;
    const unsigned n = rem / 17u, j = rem % 17u;
    const unsigned t = (b_*17u + j)*243u + n;
    const u16*   fr = fuseb + (size_t)t*512 + lane*8;
    const float* xr = x     + (size_t)o*512 + lane*8;
    u16x8 f = *(const u16x8*)fr;
    f32x4 x0 = *(const f32x4*)xr, x1 = *(const f32x4*)(xr+4);
    float y[8];
    #pragma unroll
    for (int e=0;e<4;e++){ y[e] = x0[e]+bf2f(f[e]); y[e+4] = x1[e]+bf2f(f[e+4]); }
    float s1=0.f, s2=0.f;
    #pragma unroll
    for (int e=0;e<8;e++){ s1 += y[e]; s2 += y[e]*y[e]; }
    #pragma unroll
    for (int m=1;m<64;m<<=1){ s1 += __shfl_xor(s1,m); s2 += __shfl_xor(s2,m); }
    const float mu  = s1 * (1.f/512.f);
    const float var = s2 * (1.f/512.f) - mu*mu;
    const float rstd = rsqrtf(var + 1e-5f);
    float* orow = out + (size_t)o*512 + lane*8;
    f32x4 o0, o1;
    #pragma unroll
    for (int e=0;e<4;e++){ o0[e] = (y[e]-mu)*rstd; o1[e] = (y[e+4]-mu)*rstd; }
    *(f32x4*)orow = o0; *(f32x4*)(orow+4) = o1;
}

extern "C" void kernel_launch(void* const* d_in, const int* in_sizes, int n_in,
                              void* d_out, int out_size, void* d_ws, size_t ws_size,
                              hipStream_t stream)
{
    const float* x      = (const float*)d_in[0];
    const float* W_qkv  = (const float*)d_in[1];
    const float* b_qkv  = (const float*)d_in[2];
    const float* W_q    = (const float*)d_in[3];
    const float* b_q    = (const float*)d_in[4];
    const float* W_kv   = (const float*)d_in[5];
    const float* b_kv   = (const float*)d_in[6];
    const float* W_proj = (const float*)d_in[7];
    const float* b_proj = (const float*)d_in[8];

    // workspace layout (peak ~210.6 MB):
    //   [0, 33972224)              xbf bf16 [33048+pad][512]  /  Kmix (aliased, xbf dead)
    //   [33972224, 137306112)      ws3: Q [1088][243][64], K same, VT [1088][64][256]
    //   [137306112, 171278336)     attn bf16 [33048+pad][512]
    //   [171278336, 174424064)     WcatT bf16 [3072][512]
    //   [174424064, 174948352)     WprojT bf16 [512][512]
    //   [174948352, 210599936)     VTmix bf16 [1088][64][256]
    //   fuseb bf16 aliases ws3 (dead after attn phase 1)
    char* ws = (char*)d_ws;
    u16*   xbf    = (u16*)(ws);
    u16*   kmix   = (u16*)(ws);                      // aliases xbf
    u16*   ws3    = (u16*)(ws + 33972224u);
    u16*   attn   = (u16*)(ws + 137306112u);
    u16*   WcatT  = (u16*)(ws + 171278336u);
    u16*   WprojT = (u16*)(ws + 174424064u);
    u16*   vtmix  = (u16*)(ws + 174948352u);
    u16*   fuseb  = (u16*)(ws + 33972224u);
    float* out    = (float*)d_out;

    k_cvt_xbf  <<<8262, 256, 0, stream>>>(x, xbf);
    k_cvt_wcat <<<768,  256, 0, stream>>>(W_qkv, W_q, W_kv, WcatT);
    k_cvt_wproj<<<128,  256, 0, stream>>>(W_proj, WprojT);

    // phase 0: temporal attention
    k_gemm_in<<<1554, 256, 0, stream>>>(xbf, WcatT, b_qkv, b_q, b_kv, ws3, 0);
    k_attn<<<2176, 256, 0, stream>>>(ws3, ws3 + (size_t)TE, ws3 + (size_t)2*TE, attn, 0);

    // phase 1: hierarchical attention (pre-mixed children)
    k_gemm_in<<<1554, 256, 0, stream>>>(xbf, WcatT, b_qkv, b_q, b_kv, ws3, 1536);
    k_mixk<<<8262, 256, 0, stream>>>(ws3 + (size_t)TE, kmix);
    k_mixv<<<8704, 256, 0, stream>>>(ws3 + (size_t)2*TE, vtmix);
    k_attn<<<2176, 256, 0, stream>>>(ws3, kmix, vtmix, attn, 1);

    k_gemm_proj<<<1036, 256, 0, stream>>>(attn, WprojT, b_proj, fuseb);

    k_ln<<<8262, 256, 0, stream>>>(x, fuseb, out);
}

// Round 19
// 370.225 us; speedup vs baseline: 1.1721x; 1.1721x over previous
//
#include <hip/hip_runtime.h>

typedef unsigned short u16;
typedef unsigned int u32;
typedef __attribute__((ext_vector_type(8))) short bf16x8;
typedef __attribute__((ext_vector_type(8))) u16  u16x8;
typedef __attribute__((ext_vector_type(4))) float f32x4;

#define TOK   33048      // B*J*N = 8*17*243
#define NSEQ  243
#define TE    16920576u  // elems per blocked Q/K tensor: 1088*243*64
#define GSTR  15552      // 243*64
#define VTP   256        // padded n-stride of V^T (16384 elems per g)

__device__ __forceinline__ float bf2f(u16 u){
    union { unsigned int i; float f; } v; v.i = ((unsigned int)u) << 16; return v.f;
}
__device__ __forceinline__ u16 f2bf(float f){
    union { float f; unsigned int i; } v; v.f = f;
    unsigned int r = v.i + 0x7fffu + ((v.i >> 16) & 1u);
    return (u16)(r >> 16);
}

__device__ __forceinline__ void gload_lds16(const void* g, void* l){
    __builtin_amdgcn_global_load_lds(
        (const __attribute__((address_space(1))) unsigned int*)g,
        (__attribute__((address_space(3))) unsigned int*)l, 16, 0, 0);
}

// ---------------- x -> token-major bf16 ----------------
__global__ __launch_bounds__(256) void k_cvt_xbf(const float* __restrict__ x, u16* __restrict__ xbf){
    int idx = blockIdx.x*256 + threadIdx.x;
    int t  = idx >> 6;
    int c8 = (idx & 63) << 3;
    unsigned b   = (unsigned)t / 4131u;
    unsigned rem = (unsigned)t % 4131u;
    unsigned j = rem / 243u, n = rem % 243u;
    const float* src = x + ((size_t)(b*243u + n)*17u + j)*512u + c8;
    f32x4 a = *(const f32x4*)src;
    f32x4 c = *(const f32x4*)(src+4);
    u16x8 o;
    #pragma unroll
    for (int e=0;e<4;e++){ o[e]=f2bf(a[e]); o[e+4]=f2bf(c[e]); }
    *(u16x8*)(xbf + (size_t)t*512 + c8) = o;
}

// ---------------- weight conversions ----------------
__global__ __launch_bounds__(256) void k_cvt_wcat(const float* __restrict__ Wqkv,
                                                  const float* __restrict__ Wq,
                                                  const float* __restrict__ Wkv,
                                                  u16* __restrict__ WcatT){
    int idx = blockIdx.x*256 + threadIdx.x;
    int k  = idx / 384;
    int c0 = (idx % 384) * 8;
    const float* src;
    if (c0 < 1536)      src = Wqkv + (size_t)k*1536 + c0;
    else if (c0 < 2048) src = Wq   + (size_t)k*512  + (c0 - 1536);
    else                src = Wkv  + (size_t)k*1024 + (c0 - 2048);
    f32x4 a = *(const f32x4*)src;
    f32x4 b = *(const f32x4*)(src+4);
    #pragma unroll
    for (int e=0;e<4;e++){
        WcatT[(size_t)(c0+e)*512 + k]   = f2bf(a[e]);
        WcatT[(size_t)(c0+4+e)*512 + k] = f2bf(b[e]);
    }
}

__global__ __launch_bounds__(256) void k_cvt_wproj(const float* __restrict__ Wp, u16* __restrict__ WpT){
    int idx = blockIdx.x*256 + threadIdx.x;
    int k  = idx / 64;
    int c0 = (idx % 64) * 8;
    f32x4 a = *(const f32x4*)(Wp + (size_t)k*512 + c0);
    f32x4 b = *(const f32x4*)(Wp + (size_t)k*512 + c0 + 4);
    #pragma unroll
    for (int e=0;e<4;e++){
        WpT[(size_t)(c0+e)*512 + k]   = f2bf(a[e]);
        WpT[(size_t)(c0+4+e)*512 + k] = f2bf(b[e]);
    }
}

// ---------------- input GEMM  M=33048 x N=1536(half) x K=512 ----------------
// BK=64, SINGLE 32KB LDS buffer (m97 2-barrier structure), XOR-swizzled both-sides.
// Epilogue: ONE barrier, then per-wave private LDS transpose (no block barriers).
// writes blocked Q (pre-scaled 1/8) @0, K @TE, V^T @2*TE
__global__ __launch_bounds__(256) void k_gemm_in(
    const u16* __restrict__ xbf, const u16* __restrict__ WcatT,
    const float* __restrict__ b_qkv, const float* __restrict__ b_q,
    const float* __restrict__ b_kv, u16* __restrict__ ws3, int c_off)
{
    __shared__ __align__(16) u16 smem[16384];   // 32KB: A 16KB @0, B 16KB @8192

    // bijective XCD swizzle over 3108 blocks (q=388, r=4)
    const int orig = blockIdx.x;
    const int xcd  = orig & 7;
    const int wg   = (xcd < 4 ? xcd*389 : 4*389 + (xcd-4)*388) + (orig >> 3);
    const int nt = wg % 12, mt = wg / 12;

    const int tid = threadIdx.x;
    const int w = tid >> 6, lane = tid & 63;
    const int wm = w >> 1, wn = w & 1;
    const int lg = lane >> 4, li = lane & 15;
    const int x7 = li & 7;

    const int sr8  = lane >> 3;
    const int schx = (lane & 7) ^ sr8;
    const u16* gA = xbf   + (size_t)(mt*128 + w*32 + sr8)*512 + schx*8;
    const u16* gB = WcatT + (size_t)(c_off + nt*128 + w*32 + sr8)*512 + schx*8;

    f32x4 acc[4][4];
    #pragma unroll
    for (int i=0;i<4;i++)
        #pragma unroll
        for (int jj=0;jj<4;jj++){ acc[i][jj][0]=0.f; acc[i][jj][1]=0.f; acc[i][jj][2]=0.f; acc[i][jj][3]=0.f; }

    #pragma unroll
    for (int k0 = 0; k0 < 512; k0 += 64){
        __syncthreads();                      // prior compute's LDS reads done
        #pragma unroll
        for (int i=0;i<4;i++){
            gload_lds16(gA + i*4096 + k0, smem + (w*32 + i*8)*64);
            gload_lds16(gB + i*4096 + k0, smem + 8192 + (w*32 + i*8)*64);
        }
        __syncthreads();                      // staged tile visible (vmcnt drained)
        const u16* As = smem;
        const u16* Bs = smem + 8192;
        #pragma unroll
        for (int ks=0; ks<2; ks++){
            bf16x8 av[4], bv[4];
            #pragma unroll
            for (int mf=0;mf<4;mf++){
                const int R = wm*64 + mf*16 + li;
                av[mf] = *(const bf16x8*)&As[R*64 + (((ks*4+lg) ^ x7)*8)];
            }
            #pragma unroll
            for (int nf=0;nf<4;nf++){
                const int R = wn*64 + nf*16 + li;
                bv[nf] = *(const bf16x8*)&Bs[R*64 + (((ks*4+lg) ^ x7)*8)];
            }
            #pragma unroll
            for (int mf=0;mf<4;mf++)
                #pragma unroll
                for (int nf=0;nf<4;nf++)
                    acc[mf][nf] = __builtin_amdgcn_mfma_f32_16x16x32_bf16(av[mf], bv[nf], acc[mf][nf], 0, 0, 0);
        }
    }

    float bias[4];
    #pragma unroll
    for (int nf=0;nf<4;nf++){
        const int c = c_off + nt*128 + wn*64 + nf*16 + li;
        bias[nf] = (c < 1536) ? b_qkv[c] : (c < 2048 ? b_q[c-1536] : b_kv[c-2048]);
    }

    // epilogue: ONE barrier (protect k-loop readers of smem), then per-wave-private
    // 16x72 LDS transpose tiles with NO further block barriers (L is wave-local;
    // same-wave DS ordering is guaranteed by the LDS pipe + lgkmcnt).
    __syncthreads();
    u16* L = smem + w*1152;
    const int colbase = nt*128 + wn*64;        // within this half; multiple of 64
    const int slot = colbase >> 9;             // 0=Q,1=K,2=V
    const float osc = (slot == 0) ? 0.125f : 1.0f;   // fold softmax scale into Q (exact)
    const int hh   = (colbase >> 6) & 7;
    const int rloc = lane & 15;
    const int cchunk = lane >> 4;
    const int dd = (colbase + cchunk*8) & 63;
    u16* tbase = ws3 + (size_t)slot * TE;
    u16* vt    = ws3 + (size_t)2 * TE;

    #pragma unroll
    for (int mf=0;mf<4;mf++){
        #pragma unroll
        for (int nf=0;nf<4;nf++)
            #pragma unroll
            for (int reg=0;reg<4;reg++)
                L[(lg*4+reg)*72 + nf*16 + li] = f2bf((acc[mf][nf][reg] + bias[nf]) * osc);
        const int rr_base = mt*128 + wm*64 + mf*16;
        if (slot < 2){
            const int rr = rr_base + rloc;
            if (rr < TOK){
                u16x8 v0 = *(const u16x8*)&L[rloc*72 + cchunk*8];
                u16x8 v1 = *(const u16x8*)&L[rloc*72 + 32 + cchunk*8];
                const unsigned bj = (unsigned)rr / 243u;
                const unsigned n  = (unsigned)rr % 243u;
                u16* dst = tbase + ((size_t)(bj*8u + hh)*243u + n)*64u + dd;
                *(u16x8*)dst      = v0;
                *(u16x8*)(dst+32) = v1;
            }
        } else {
            u16 colv[16];
            #pragma unroll
            for (int r=0;r<16;r++) colv[r] = L[r*72 + lane];
            if (rr_base < TOK){
                const unsigned bj0 = (unsigned)rr_base / 243u;
                const unsigned n0  = (unsigned)rr_base % 243u;
                if (n0 <= 227 && rr_base + 15 < TOK){
                    u16x8 vlo, vhi;
                    #pragma unroll
                    for (int e=0;e<8;e++){ vlo[e]=colv[e]; vhi[e]=colv[e+8]; }
                    u16* dst = vt + ((size_t)(bj0*8u + hh)*64u + lane)*VTP + n0;
                    *(u16x8*)dst     = vlo;
                    *(u16x8*)(dst+8) = vhi;
                } else {
                    for (int r=0;r<16;r++){
                        const int rr = rr_base + r;
                        if (rr < TOK){
                            const unsigned bjr = (unsigned)rr / 243u;
                            const unsigned nr  = (unsigned)rr % 243u;
                            vt[((size_t)(bjr*8u + hh)*64u + lane)*VTP + nr] = colv[r];
                        }
                    }
                }
            }
        }
    }
}

// ---------------- child-mean pre-mix kernels ----------------
__constant__ int g_child[17][3] = {
  {1,4,7},{2,-1,-1},{3,-1,-1},{3,-1,-1},{5,-1,-1},{6,-1,-1},{6,-1,-1},{8,-1,-1},
  {9,11,14},{10,-1,-1},{10,-1,-1},{12,-1,-1},{13,-1,-1},{13,-1,-1},{15,-1,-1},
  {16,-1,-1},{16,-1,-1}};
__constant__ float g_cw[17] = {0.33333333f,1,1,1,1,1,1,1,0.33333333f,1,1,1,1,1,1,1,1};

__global__ __launch_bounds__(256) void k_mixk(const u16* __restrict__ Kraw, u16* __restrict__ Kmix){
    const int c = blockIdx.x*256 + threadIdx.x;    // 2,115,072 = 1088*1944
    const int g = c / 1944;
    const int off = (c % 1944) * 8;
    const int bj = g >> 3, h = g & 7;
    const int b_ = bj / 17, j_ = bj % 17;
    const float wgt = g_cw[j_];
    float acc[8];
    #pragma unroll
    for (int e=0;e<8;e++) acc[e]=0.f;
    #pragma unroll
    for (int ci=0;ci<3;ci++){
        const int cj = g_child[j_][ci];
        if (cj >= 0){
            const u16x8 v = *(const u16x8*)(Kraw + (size_t)((b_*17+cj)*8+h)*GSTR + off);
            #pragma unroll
            for (int e=0;e<8;e++) acc[e] += wgt*bf2f(v[e]);
        }
    }
    u16x8 o;
    #pragma unroll
    for (int e=0;e<8;e++) o[e]=f2bf(acc[e]);
    *(u16x8*)(Kmix + (size_t)g*GSTR + off) = o;
}

__global__ __launch_bounds__(256) void k_mixv(const u16* __restrict__ VTraw, u16* __restrict__ VTmix){
    const int c = blockIdx.x*256 + threadIdx.x;    // 2,228,224 = 1088*2048
    const int g = c / 2048;
    const int off = (c % 2048) * 8;
    const int bj = g >> 3, h = g & 7;
    const int b_ = bj / 17, j_ = bj % 17;
    const float wgt = g_cw[j_];
    float acc[8];
    #pragma unroll
    for (int e=0;e<8;e++) acc[e]=0.f;
    #pragma unroll
    for (int ci=0;ci<3;ci++){
        const int cj = g_child[j_][ci];
        if (cj >= 0){
            const u16x8 v = *(const u16x8*)(VTraw + (size_t)((b_*17+cj)*8+h)*16384u + off);
            #pragma unroll
            for (int e=0;e<8;e++) acc[e] += wgt*bf2f(v[e]);
        }
    }
    u16x8 o;
    #pragma unroll
    for (int e=0;e<8;e++) o[e]=f2bf(acc[e]);
    *(u16x8*)(VTmix + (size_t)g*16384u + off) = o;
}

// ---------------- fused attention: flash-style, async staging, counted vmcnt dbuf ------
__global__ __launch_bounds__(256, 3) void k_attn(
    const u16* __restrict__ Qb, const u16* __restrict__ Kb,
    const u16* __restrict__ VTb, u16* __restrict__ attn, int rmw)
{
    __shared__ __align__(16) u16 smem[16384];      // 32KB

    // XCD-grouping swizzle: both halves of a g land on one XCD
    const int orig = blockIdx.x;                   // 2176
    const int xcd  = orig & 7;
    const int lin  = orig >> 3;
    const int p2   = lin & 1;
    const int g    = (lin >> 1)*8 + xcd;
    const int bj = g >> 3, h = g & 7;

    const int tid = threadIdx.x, lane = tid & 63, w = tid >> 6;
    const int lg = lane >> 4, li = lane & 15;

    // Q (pre-scaled by 1/8 at GEMM)
    const int qrowA = p2*128 + w*16;
    const int qrowB = qrowA + 64;
    bf16x8 qA0 = {0,0,0,0,0,0,0,0}, qA1 = qA0, qB0 = qA0, qB1 = qA0;
    {
        const int qrA = qrowA + li;
        const u16* qp = Qb + (size_t)g*GSTR + (size_t)qrA*64;
        qA0 = *(const bf16x8*)(qp + lg*8);
        qA1 = *(const bf16x8*)(qp + 32 + lg*8);
        const int qrB = qrowB + li;
        if (qrB < NSEQ){
            const u16* qp2 = Qb + (size_t)g*GSTR + (size_t)qrB*64;
            qB0 = *(const bf16x8*)(qp2 + lg*8);
            qB1 = *(const bf16x8*)(qp2 + 32 + lg*8);
        }
    }

    // staging source (inverse-swizzled): lane l covers row (l>>3), chunk (l&7)^(l>>3)
    const int schx = (lane & 7) ^ (lane >> 3);
    const u16* ksrc = Kb  + (size_t)g*GSTR   + (size_t)(w*16 + (lane>>3))*64  + schx*8;
    const u16* vsrc = VTb + (size_t)g*16384u + (size_t)(w*16 + (lane>>3))*VTP + schx*8;

    const int laneA = li + 32*(lg & 1);
    const int laneB = laneA + 16;
    const bool sel = (lg >> 1) != 0;
    const int x7 = li & 7;

    float sumA = 0.f, sumB = 0.f;
    f32x4 oA[4], oB[4];
    #pragma unroll
    for (int dn=0;dn<4;dn++){
        oA[dn][0]=0.f; oA[dn][1]=0.f; oA[dn][2]=0.f; oA[dn][3]=0.f;
        oB[dn][0]=0.f; oB[dn][1]=0.f; oB[dn][2]=0.f; oB[dn][3]=0.f;
    }

    // prologue: stage t=0 into buffer 0 (4 loads in flight)
    {
        char* b0 = (char*)smem;
        gload_lds16(ksrc,         b0 + w*2048);
        gload_lds16(ksrc + 512,   b0 + w*2048 + 1024);
        gload_lds16(vsrc,         b0 + 8192 + w*2048);
        gload_lds16(vsrc + 8*VTP, b0 + 8192 + w*2048 + 1024);
    }

    int cur = 0;
    #pragma unroll
    for (int t=0; t<4; t++){
        if (t < 3){
            char* nb = (char*)smem + (cur^1)*16384;
            gload_lds16(ksrc + (size_t)(t+1)*4096,        nb + w*2048);
            gload_lds16(ksrc + (size_t)(t+1)*4096 + 512,  nb + w*2048 + 1024);
            gload_lds16(vsrc + (t+1)*64,                  nb + 8192 + w*2048);
            gload_lds16(vsrc + (t+1)*64 + 8*VTP,          nb + 8192 + w*2048 + 1024);
            asm volatile("s_waitcnt vmcnt(4)");   // tile t landed; t+1 stays in flight
        } else {
            asm volatile("s_waitcnt vmcnt(0)");
        }
        __builtin_amdgcn_s_barrier();
        char* kl = (char*)smem + cur*16384;
        char* vl = kl + 8192;

        #pragma unroll
        for (int half=0; half<2; half++){
            u32 lo2A[2], hi2A[2], lo2B[2], hi2B[2];
            #pragma unroll
            for (int t2=0; t2<2; t2++){
                const int nt2l = half*2 + t2;       // 0..3
                const int row  = nt2l*16 + li;      // local K row
                const bf16x8 kb0 = *(const bf16x8*)(kl + row*128 + (((lg  ) ^ x7)<<4));
                const bf16x8 kb1 = *(const bf16x8*)(kl + row*128 + (((4+lg) ^ x7)<<4));
                f32x4 sA; sA[0]=0.f; sA[1]=0.f; sA[2]=0.f; sA[3]=0.f;
                f32x4 sB = sA;
                sA = __builtin_amdgcn_mfma_f32_16x16x32_bf16(kb0, qA0, sA, 0,0,0);
                sA = __builtin_amdgcn_mfma_f32_16x16x32_bf16(kb1, qA1, sA, 0,0,0);
                sB = __builtin_amdgcn_mfma_f32_16x16x32_bf16(kb0, qB0, sB, 0,0,0);
                sB = __builtin_amdgcn_mfma_f32_16x16x32_bf16(kb1, qB1, sB, 0,0,0);
                if (t == 3 && nt2l == 3){           // k = 240 + lg*4 + r >= 243
                    sA[3] = -1e30f; sB[3] = -1e30f;
                    if (lg){ sA[0]=-1e30f; sA[1]=-1e30f; sA[2]=-1e30f;
                             sB[0]=-1e30f; sB[1]=-1e30f; sB[2]=-1e30f; }
                }
                const float a0 = __expf(sA[0]);
                const float a1 = __expf(sA[1]);
                const float a2 = __expf(sA[2]);
                const float a3 = __expf(sA[3]);
                sumA += (a0+a1)+(a2+a3);
                lo2A[t2] = (u32)f2bf(a0) | ((u32)f2bf(a1) << 16);
                hi2A[t2] = (u32)f2bf(a2) | ((u32)f2bf(a3) << 16);
                const float b0 = __expf(sB[0]);
                const float b1 = __expf(sB[1]);
                const float b2 = __expf(sB[2]);
                const float b3 = __expf(sB[3]);
                sumB += (b0+b1)+(b2+b3);
                lo2B[t2] = (u32)f2bf(b0) | ((u32)f2bf(b1) << 16);
                hi2B[t2] = (u32)f2bf(b2) | ((u32)f2bf(b3) << 16);
            }
            // shuffle -> PV A-fragments: pa elem e = P[q=li][k=kt*32+lg*8+e]
            bf16x8 paA, paB;
            {
                u32 a0 = __shfl((int)lo2A[0], laneA), a1 = __shfl((int)lo2A[1], laneA);
                u32 b0 = __shfl((int)hi2A[0], laneA), b1 = __shfl((int)hi2A[1], laneA);
                u32 c0 = __shfl((int)lo2A[0], laneB), c1 = __shfl((int)lo2A[1], laneB);
                u32 d0 = __shfl((int)hi2A[0], laneB), d1 = __shfl((int)hi2A[1], laneB);
                union { u32 u[4]; bf16x8 v; } pk;
                pk.u[0] = sel ? a1 : a0;
                pk.u[1] = sel ? b1 : b0;
                pk.u[2] = sel ? c1 : c0;
                pk.u[3] = sel ? d1 : d0;
                paA = pk.v;
            }
            {
                u32 a0 = __shfl((int)lo2B[0], laneA), a1 = __shfl((int)lo2B[1], laneA);
                u32 b0 = __shfl((int)hi2B[0], laneA), b1 = __shfl((int)hi2B[1], laneA);
                u32 c0 = __shfl((int)lo2B[0], laneB), c1 = __shfl((int)lo2B[1], laneB);
                u32 d0 = __shfl((int)hi2B[0], laneB), d1 = __shfl((int)hi2B[1], laneB);
                union { u32 u[4]; bf16x8 v; } pk;
                pk.u[0] = sel ? a1 : a0;
                pk.u[1] = sel ? b1 : b0;
                pk.u[2] = sel ? c1 : c0;
                pk.u[3] = sel ? d1 : d0;
                paB = pk.v;
            }
            #pragma unroll
            for (int dn=0;dn<4;dn++){
                const int d = dn*16 + li;
                const bf16x8 vb = *(const bf16x8*)(vl + d*128 + ((((half<<2)+lg) ^ x7)<<4));
                oA[dn] = __builtin_amdgcn_mfma_f32_16x16x32_bf16(paA, vb, oA[dn], 0,0,0);
                oB[dn] = __builtin_amdgcn_mfma_f32_16x16x32_bf16(paB, vb, oB[dn], 0,0,0);
            }
        }
        __builtin_amdgcn_s_barrier();    // all reads of buf[cur] done before overwrite
        cur ^= 1;
    }

    sumA += __shfl_xor(sumA,16); sumA += __shfl_xor(sumA,32);
    sumB += __shfl_xor(sumB,16); sumB += __shfl_xor(sumB,32);
    const float invA = 1.f/sumA;
    const float invB = 1.f/sumB;
    float invrA[4], invrB[4];
    #pragma unroll
    for (int r=0;r<4;r++){
        invrA[r] = __shfl(invA, lg*4+r);
        invrB[r] = __shfl(invB, lg*4+r);
    }

    #pragma unroll
    for (int dn=0;dn<4;dn++){
        #pragma unroll
        for (int r=0;r<4;r++){
            const int qrow = qrowA + lg*4 + r;
            const size_t off = ((size_t)bj*243 + qrow)*512 + h*64 + dn*16 + li;
            float val = oA[dn][r] * invrA[r];
            if (rmw) val += bf2f(attn[off]);
            attn[off] = f2bf(val);
        }
        #pragma unroll
        for (int r=0;r<4;r++){
            const int qrow = qrowB + lg*4 + r;
            if (qrow < NSEQ){
                const size_t off = ((size_t)bj*243 + qrow)*512 + h*64 + dn*16 + li;
                float val = oB[dn][r] * invrB[r];
                if (rmw) val += bf2f(attn[off]);
                attn[off] = f2bf(val);
            }
        }
    }
}

// ---------------- projection GEMM  M=33048 x N=512 x K=512 -> bf16 fuse ----------------
// BK=64, single 32KB LDS (m97 structure), XOR-swizzled.
__global__ __launch_bounds__(256) void k_gemm_proj(
    const u16* __restrict__ attnb, const u16* __restrict__ WprojT,
    const float* __restrict__ b_proj, u16* __restrict__ fuseb)
{
    __shared__ __align__(16) u16 smem[16384];   // 32KB: A 16KB @0, B 16KB @8192

    const int orig = blockIdx.x;
    const int xcd  = orig & 7;
    const int wg   = (xcd < 4 ? xcd*130 : 4*130 + (xcd-4)*129) + (orig >> 3);
    const int nt = wg & 3, mt = wg >> 2;

    const int tid = threadIdx.x;
    const int w = tid >> 6, lane = tid & 63;
    const int wm = w >> 1, wn = w & 1;
    const int lg = lane >> 4, li = lane & 15;
    const int x7 = li & 7;

    const int sr8  = lane >> 3;
    const int schx = (lane & 7) ^ sr8;
    const u16* gA = attnb  + (size_t)(mt*128 + w*32 + sr8)*512 + schx*8;
    const u16* gB = WprojT + (size_t)(nt*128 + w*32 + sr8)*512 + schx*8;

    f32x4 acc[4][4];
    #pragma unroll
    for (int i=0;i<4;i++)
        #pragma unroll
        for (int jj=0;jj<4;jj++){ acc[i][jj][0]=0.f; acc[i][jj][1]=0.f; acc[i][jj][2]=0.f; acc[i][jj][3]=0.f; }

    #pragma unroll
    for (int k0 = 0; k0 < 512; k0 += 64){
        __syncthreads();
        #pragma unroll
        for (int i=0;i<4;i++){
            gload_lds16(gA + i*4096 + k0, smem + (w*32 + i*8)*64);
            gload_lds16(gB + i*4096 + k0, smem + 8192 + (w*32 + i*8)*64);
        }
        __syncthreads();
        const u16* As = smem;
        const u16* Bs = smem + 8192;
        #pragma unroll
        for (int ks=0; ks<2; ks++){
            bf16x8 av[4], bv[4];
            #pragma unroll
            for (int mf=0;mf<4;mf++){
                const int R = wm*64 + mf*16 + li;
                av[mf] = *(const bf16x8*)&As[R*64 + (((ks*4+lg) ^ x7)*8)];
            }
            #pragma unroll
            for (int nf=0;nf<4;nf++){
                const int R = wn*64 + nf*16 + li;
                bv[nf] = *(const bf16x8*)&Bs[R*64 + (((ks*4+lg) ^ x7)*8)];
            }
            #pragma unroll
            for (int mf=0;mf<4;mf++)
                #pragma unroll
                for (int nf=0;nf<4;nf++)
                    acc[mf][nf] = __builtin_amdgcn_mfma_f32_16x16x32_bf16(av[mf], bv[nf], acc[mf][nf], 0, 0, 0);
        }
    }

    #pragma unroll
    for (int mf=0;mf<4;mf++)
        #pragma unroll
        for (int reg=0;reg<4;reg++){
            const int rr = mt*128 + wm*64 + mf*16 + lg*4 + reg;
            if (rr < TOK){
                #pragma unroll
                for (int nf=0;nf<4;nf++){
                    const int c = nt*128 + wn*64 + nf*16 + li;
                    fuseb[(size_t)rr*512 + c] = f2bf(acc[mf][nf][reg] + b_proj[c]);
                }
            }
        }
}

// ---------------- residual + LayerNorm (bf16 fuse, (b,j,n)->(b,n,j) permute) ------------
__global__ __launch_bounds__(256) void k_ln(
    const float* __restrict__ x, const u16* __restrict__ fuseb, float* __restrict__ out)
{
    const int w = threadIdx.x >> 6, lane = threadIdx.x & 63;
    const int o = blockIdx.x*4 + w;
    const unsigned b_  = (unsigned)o / 4131u;
    const unsigned rem = (unsigned)o % 4131u;
    const unsigned n = rem / 17u, j = rem % 17u;
    const unsigned t = (b_*17u + j)*243u + n;
    const u16*   fr = fuseb + (size_t)t*512 + lane*8;
    const float* xr = x     + (size_t)o*512 + lane*8;
    u16x8 f = *(const u16x8*)fr;
    f32x4 x0 = *(const f32x4*)xr, x1 = *(const f32x4*)(xr+4);
    float y[8];
    #pragma unroll
    for (int e=0;e<4;e++){ y[e] = x0[e]+bf2f(f[e]); y[e+4] = x1[e]+bf2f(f[e+4]); }
    float s1=0.f, s2=0.f;
    #pragma unroll
    for (int e=0;e<8;e++){ s1 += y[e]; s2 += y[e]*y[e]; }
    #pragma unroll
    for (int m=1;m<64;m<<=1){ s1 += __shfl_xor(s1,m); s2 += __shfl_xor(s2,m); }
    const float mu  = s1 * (1.f/512.f);
    const float var = s2 * (1.f/512.f) - mu*mu;
    const float rstd = rsqrtf(var + 1e-5f);
    float* orow = out + (size_t)o*512 + lane*8;
    f32x4 o0, o1;
    #pragma unroll
    for (int e=0;e<4;e++){ o0[e] = (y[e]-mu)*rstd; o1[e] = (y[e+4]-mu)*rstd; }
    *(f32x4*)orow = o0; *(f32x4*)(orow+4) = o1;
}

extern "C" void kernel_launch(void* const* d_in, const int* in_sizes, int n_in,
                              void* d_out, int out_size, void* d_ws, size_t ws_size,
                              hipStream_t stream)
{
    const float* x      = (const float*)d_in[0];
    const float* W_qkv  = (const float*)d_in[1];
    const float* b_qkv  = (const float*)d_in[2];
    const float* W_q    = (const float*)d_in[3];
    const float* b_q    = (const float*)d_in[4];
    const float* W_kv   = (const float*)d_in[5];
    const float* b_kv   = (const float*)d_in[6];
    const float* W_proj = (const float*)d_in[7];
    const float* b_proj = (const float*)d_in[8];

    // workspace layout (peak ~210.6 MB):
    //   [0, 33972224)              xbf bf16 [33048+pad][512]  /  Kmix (aliased, xbf dead)
    //   [33972224, 137306112)      ws3: Q [1088][243][64], K same, VT [1088][64][256]
    //   [137306112, 171278336)     attn bf16 [33048+pad][512]
    //   [171278336, 174424064)     WcatT bf16 [3072][512]
    //   [174424064, 174948352)     WprojT bf16 [512][512]
    //   [174948352, 210599936)     VTmix bf16 [1088][64][256]
    //   fuseb bf16 aliases ws3 (dead after attn phase 1)
    char* ws = (char*)d_ws;
    u16*   xbf    = (u16*)(ws);
    u16*   kmix   = (u16*)(ws);                      // aliases xbf
    u16*   ws3    = (u16*)(ws + 33972224u);
    u16*   attn   = (u16*)(ws + 137306112u);
    u16*   WcatT  = (u16*)(ws + 171278336u);
    u16*   WprojT = (u16*)(ws + 174424064u);
    u16*   vtmix  = (u16*)(ws + 174948352u);
    u16*   fuseb  = (u16*)(ws + 33972224u);
    float* out    = (float*)d_out;

    k_cvt_xbf  <<<8262, 256, 0, stream>>>(x, xbf);
    k_cvt_wcat <<<768,  256, 0, stream>>>(W_qkv, W_q, W_kv, WcatT);
    k_cvt_wproj<<<128,  256, 0, stream>>>(W_proj, WprojT);

    // phase 0: temporal attention
    k_gemm_in<<<3108, 256, 0, stream>>>(xbf, WcatT, b_qkv, b_q, b_kv, ws3, 0);
    k_attn<<<2176, 256, 0, stream>>>(ws3, ws3 + (size_t)TE, ws3 + (size_t)2*TE, attn, 0);

    // phase 1: hierarchical attention (pre-mixed children)
    k_gemm_in<<<3108, 256, 0, stream>>>(xbf, WcatT, b_qkv, b_q, b_kv, ws3, 1536);
    k_mixk<<<8262, 256, 0, stream>>>(ws3 + (size_t)TE, kmix);
    k_mixv<<<8704, 256, 0, stream>>>(ws3 + (size_t)2*TE, vtmix);
    k_attn<<<2176, 256, 0, stream>>>(ws3, kmix, vtmix, attn, 1);

    k_gemm_proj<<<1036, 256, 0, stream>>>(attn, WprojT, b_proj, fuseb);

    k_ln<<<8262, 256, 0, stream>>>(x, fuseb, out);
}

// Round 20
// 359.552 us; speedup vs baseline: 1.2069x; 1.0297x over previous
//
#include <hip/hip_runtime.h>

typedef unsigned short u16;
typedef unsigned int u32;
typedef __attribute__((ext_vector_type(8))) short bf16x8;
typedef __attribute__((ext_vector_type(8))) u16  u16x8;
typedef __attribute__((ext_vector_type(4))) float f32x4;

#define TOK   33048      // B*J*N = 8*17*243
#define NSEQ  243
#define TE    16920576u  // elems per blocked Q/K tensor: 1088*243*64
#define GSTR  15552      // 243*64
#define VTP   256        // padded n-stride of V^T (16384 elems per g)

__device__ __forceinline__ float bf2f(u16 u){
    union { unsigned int i; float f; } v; v.i = ((unsigned int)u) << 16; return v.f;
}
__device__ __forceinline__ u16 f2bf(float f){
    union { float f; unsigned int i; } v; v.f = f;
    unsigned int r = v.i + 0x7fffu + ((v.i >> 16) & 1u);
    return (u16)(r >> 16);
}

__device__ __forceinline__ void gload_lds16(const void* g, void* l){
    __builtin_amdgcn_global_load_lds(
        (const __attribute__((address_space(1))) unsigned int*)g,
        (__attribute__((address_space(3))) unsigned int*)l, 16, 0, 0);
}

__constant__ int g_child[17][3] = {
  {1,4,7},{2,-1,-1},{3,-1,-1},{3,-1,-1},{5,-1,-1},{6,-1,-1},{6,-1,-1},{8,-1,-1},
  {9,11,14},{10,-1,-1},{10,-1,-1},{12,-1,-1},{13,-1,-1},{13,-1,-1},{15,-1,-1},
  {16,-1,-1},{16,-1,-1}};
__constant__ float g_cw[17] = {0.33333333f,1,1,1,1,1,1,1,0.33333333f,1,1,1,1,1,1,1,1};

// ---------------- x -> token-major bf16 ----------------
__global__ __launch_bounds__(256) void k_cvt_xbf(const float* __restrict__ x, u16* __restrict__ xbf){
    int idx = blockIdx.x*256 + threadIdx.x;
    int t  = idx >> 6;
    int c8 = (idx & 63) << 3;
    unsigned b   = (unsigned)t / 4131u;
    unsigned rem = (unsigned)t % 4131u;
    unsigned j = rem / 243u, n = rem % 243u;
    const float* src = x + ((size_t)(b*243u + n)*17u + j)*512u + c8;
    f32x4 a = *(const f32x4*)src;
    f32x4 c = *(const f32x4*)(src+4);
    u16x8 o;
    #pragma unroll
    for (int e=0;e<4;e++){ o[e]=f2bf(a[e]); o[e+4]=f2bf(c[e]); }
    *(u16x8*)(xbf + (size_t)t*512 + c8) = o;
}

// ---------------- child-mean mix of x (token-major bf16 -> token-major bf16) ----------
__global__ __launch_bounds__(256) void k_mixx(const u16* __restrict__ xbf, u16* __restrict__ xmix){
    int idx = blockIdx.x*256 + threadIdx.x;   // 33048*64
    int t  = idx >> 6;
    int c8 = (idx & 63) << 3;
    unsigned b   = (unsigned)t / 4131u;
    unsigned rem = (unsigned)t % 4131u;
    unsigned j = rem / 243u, n = rem % 243u;
    const float wgt = g_cw[j];
    float acc[8];
    #pragma unroll
    for (int e=0;e<8;e++) acc[e]=0.f;
    #pragma unroll
    for (int ci=0;ci<3;ci++){
        const int cj = g_child[j][ci];
        if (cj >= 0){
            const u16x8 v = *(const u16x8*)(xbf + ((size_t)(b*17u+cj)*243u + n)*512u + c8);
            #pragma unroll
            for (int e=0;e<8;e++) acc[e] += wgt*bf2f(v[e]);
        }
    }
    u16x8 o;
    #pragma unroll
    for (int e=0;e<8;e++) o[e]=f2bf(acc[e]);
    *(u16x8*)(xmix + (size_t)t*512 + c8) = o;
}

// ---------------- weight conversions ----------------
__global__ __launch_bounds__(256) void k_cvt_wcat(const float* __restrict__ Wqkv,
                                                  const float* __restrict__ Wq,
                                                  const float* __restrict__ Wkv,
                                                  u16* __restrict__ WcatT){
    int idx = blockIdx.x*256 + threadIdx.x;
    int k  = idx / 384;
    int c0 = (idx % 384) * 8;
    const float* src;
    if (c0 < 1536)      src = Wqkv + (size_t)k*1536 + c0;
    else if (c0 < 2048) src = Wq   + (size_t)k*512  + (c0 - 1536);
    else                src = Wkv  + (size_t)k*1024 + (c0 - 2048);
    f32x4 a = *(const f32x4*)src;
    f32x4 b = *(const f32x4*)(src+4);
    #pragma unroll
    for (int e=0;e<4;e++){
        WcatT[(size_t)(c0+e)*512 + k]   = f2bf(a[e]);
        WcatT[(size_t)(c0+4+e)*512 + k] = f2bf(b[e]);
    }
}

__global__ __launch_bounds__(256) void k_cvt_wproj(const float* __restrict__ Wp, u16* __restrict__ WpT){
    int idx = blockIdx.x*256 + threadIdx.x;
    int k  = idx / 64;
    int c0 = (idx % 64) * 8;
    f32x4 a = *(const f32x4*)(Wp + (size_t)k*512 + c0);
    f32x4 b = *(const f32x4*)(Wp + (size_t)k*512 + c0 + 4);
    #pragma unroll
    for (int e=0;e<4;e++){
        WpT[(size_t)(c0+e)*512 + k]   = f2bf(a[e]);
        WpT[(size_t)(c0+4+e)*512 + k] = f2bf(b[e]);
    }
}

// ---------------- input GEMM  M=33048 x N=1536(half) x K=512 ----------------
// BK=64, single 32KB LDS (m97 2-barrier structure), XOR-swizzled both-sides.
// A-panel per block: Q columns (nt<4) read xq; K/V columns read xkv (phase 1: pre-mixed x).
// writes blocked Q (pre-scaled 1/8) @0, K @TE, V^T @2*TE
__global__ __launch_bounds__(256) void k_gemm_in(
    const u16* __restrict__ xq, const u16* __restrict__ xkv,
    const u16* __restrict__ WcatT,
    const float* __restrict__ b_qkv, const float* __restrict__ b_q,
    const float* __restrict__ b_kv, u16* __restrict__ ws3, int c_off)
{
    __shared__ __align__(16) u16 smem[16384];   // 32KB: A 16KB @0, B 16KB @8192

    // bijective XCD swizzle over 3108 blocks (q=388, r=4)
    const int orig = blockIdx.x;
    const int xcd  = orig & 7;
    const int wg   = (xcd < 4 ? xcd*389 : 4*389 + (xcd-4)*388) + (orig >> 3);
    const int nt = wg % 12, mt = wg / 12;

    const int tid = threadIdx.x;
    const int w = tid >> 6, lane = tid & 63;
    const int wm = w >> 1, wn = w & 1;
    const int lg = lane >> 4, li = lane & 15;
    const int x7 = li & 7;

    const u16* Abase = (nt < 4) ? xq : xkv;     // block-uniform (slot = nt>>2)

    const int sr8  = lane >> 3;
    const int schx = (lane & 7) ^ sr8;
    const u16* gA = Abase + (size_t)(mt*128 + w*32 + sr8)*512 + schx*8;
    const u16* gB = WcatT + (size_t)(c_off + nt*128 + w*32 + sr8)*512 + schx*8;

    f32x4 acc[4][4];
    #pragma unroll
    for (int i=0;i<4;i++)
        #pragma unroll
        for (int jj=0;jj<4;jj++){ acc[i][jj][0]=0.f; acc[i][jj][1]=0.f; acc[i][jj][2]=0.f; acc[i][jj][3]=0.f; }

    #pragma unroll
    for (int k0 = 0; k0 < 512; k0 += 64){
        __syncthreads();                      // prior compute's LDS reads done
        #pragma unroll
        for (int i=0;i<4;i++){
            gload_lds16(gA + i*4096 + k0, smem + (w*32 + i*8)*64);
            gload_lds16(gB + i*4096 + k0, smem + 8192 + (w*32 + i*8)*64);
        }
        __syncthreads();                      // staged tile visible (vmcnt drained)
        const u16* As = smem;
        const u16* Bs = smem + 8192;
        #pragma unroll
        for (int ks=0; ks<2; ks++){
            bf16x8 av[4], bv[4];
            #pragma unroll
            for (int mf=0;mf<4;mf++){
                const int R = wm*64 + mf*16 + li;
                av[mf] = *(const bf16x8*)&As[R*64 + (((ks*4+lg) ^ x7)*8)];
            }
            #pragma unroll
            for (int nf=0;nf<4;nf++){
                const int R = wn*64 + nf*16 + li;
                bv[nf] = *(const bf16x8*)&Bs[R*64 + (((ks*4+lg) ^ x7)*8)];
            }
            #pragma unroll
            for (int mf=0;mf<4;mf++)
                #pragma unroll
                for (int nf=0;nf<4;nf++)
                    acc[mf][nf] = __builtin_amdgcn_mfma_f32_16x16x32_bf16(av[mf], bv[nf], acc[mf][nf], 0, 0, 0);
        }
    }

    float bias[4];
    #pragma unroll
    for (int nf=0;nf<4;nf++){
        const int c = c_off + nt*128 + wn*64 + nf*16 + li;
        bias[nf] = (c < 1536) ? b_qkv[c] : (c < 2048 ? b_q[c-1536] : b_kv[c-2048]);
    }

    // epilogue: ONE barrier, then per-wave private LDS transpose (no block barriers)
    __syncthreads();
    u16* L = smem + w*1152;
    const int colbase = nt*128 + wn*64;        // within this half; multiple of 64
    const int slot = colbase >> 9;             // 0=Q,1=K,2=V
    const float osc = (slot == 0) ? 0.125f : 1.0f;   // fold softmax scale into Q (exact)
    const int hh   = (colbase >> 6) & 7;
    const int rloc = lane & 15;
    const int cchunk = lane >> 4;
    const int dd = (colbase + cchunk*8) & 63;
    u16* tbase = ws3 + (size_t)slot * TE;
    u16* vt    = ws3 + (size_t)2 * TE;

    #pragma unroll
    for (int mf=0;mf<4;mf++){
        #pragma unroll
        for (int nf=0;nf<4;nf++)
            #pragma unroll
            for (int reg=0;reg<4;reg++)
                L[(lg*4+reg)*72 + nf*16 + li] = f2bf((acc[mf][nf][reg] + bias[nf]) * osc);
        const int rr_base = mt*128 + wm*64 + mf*16;
        if (slot < 2){
            const int rr = rr_base + rloc;
            if (rr < TOK){
                u16x8 v0 = *(const u16x8*)&L[rloc*72 + cchunk*8];
                u16x8 v1 = *(const u16x8*)&L[rloc*72 + 32 + cchunk*8];
                const unsigned bj = (unsigned)rr / 243u;
                const unsigned n  = (unsigned)rr % 243u;
                u16* dst = tbase + ((size_t)(bj*8u + hh)*243u + n)*64u + dd;
                *(u16x8*)dst      = v0;
                *(u16x8*)(dst+32) = v1;
            }
        } else {
            u16 colv[16];
            #pragma unroll
            for (int r=0;r<16;r++) colv[r] = L[r*72 + lane];
            if (rr_base < TOK){
                const unsigned bj0 = (unsigned)rr_base / 243u;
                const unsigned n0  = (unsigned)rr_base % 243u;
                if (n0 <= 227 && rr_base + 15 < TOK){
                    u16x8 vlo, vhi;
                    #pragma unroll
                    for (int e=0;e<8;e++){ vlo[e]=colv[e]; vhi[e]=colv[e+8]; }
                    u16* dst = vt + ((size_t)(bj0*8u + hh)*64u + lane)*VTP + n0;
                    *(u16x8*)dst     = vlo;
                    *(u16x8*)(dst+8) = vhi;
                } else {
                    for (int r=0;r<16;r++){
                        const int rr = rr_base + r;
                        if (rr < TOK){
                            const unsigned bjr = (unsigned)rr / 243u;
                            const unsigned nr  = (unsigned)rr % 243u;
                            vt[((size_t)(bjr*8u + hh)*64u + lane)*VTP + nr] = colv[r];
                        }
                    }
                }
            }
        }
    }
}

// ---------------- fused attention: flash-style, async staging, counted vmcnt dbuf ------
__global__ __launch_bounds__(256, 3) void k_attn(
    const u16* __restrict__ Qb, const u16* __restrict__ Kb,
    const u16* __restrict__ VTb, u16* __restrict__ attn, int rmw)
{
    __shared__ __align__(16) u16 smem[16384];      // 32KB

    // XCD-grouping swizzle: both halves of a g land on one XCD
    const int orig = blockIdx.x;                   // 2176
    const int xcd  = orig & 7;
    const int lin  = orig >> 3;
    const int p2   = lin & 1;
    const int g    = (lin >> 1)*8 + xcd;
    const int bj = g >> 3, h = g & 7;

    const int tid = threadIdx.x, lane = tid & 63, w = tid >> 6;
    const int lg = lane >> 4, li = lane & 15;

    // Q (pre-scaled by 1/8 at GEMM)
    const int qrowA = p2*128 + w*16;
    const int qrowB = qrowA + 64;
    bf16x8 qA0 = {0,0,0,0,0,0,0,0}, qA1 = qA0, qB0 = qA0, qB1 = qA0;
    {
        const int qrA = qrowA + li;
        const u16* qp = Qb + (size_t)g*GSTR + (size_t)qrA*64;
        qA0 = *(const bf16x8*)(qp + lg*8);
        qA1 = *(const bf16x8*)(qp + 32 + lg*8);
        const int qrB = qrowB + li;
        if (qrB < NSEQ){
            const u16* qp2 = Qb + (size_t)g*GSTR + (size_t)qrB*64;
            qB0 = *(const bf16x8*)(qp2 + lg*8);
            qB1 = *(const bf16x8*)(qp2 + 32 + lg*8);
        }
    }

    // staging source (inverse-swizzled): lane l covers row (l>>3), chunk (l&7)^(l>>3)
    const int schx = (lane & 7) ^ (lane >> 3);
    const u16* ksrc = Kb  + (size_t)g*GSTR   + (size_t)(w*16 + (lane>>3))*64  + schx*8;
    const u16* vsrc = VTb + (size_t)g*16384u + (size_t)(w*16 + (lane>>3))*VTP + schx*8;

    const int laneA = li + 32*(lg & 1);
    const int laneB = laneA + 16;
    const bool sel = (lg >> 1) != 0;
    const int x7 = li & 7;

    float sumA = 0.f, sumB = 0.f;
    f32x4 oA[4], oB[4];
    #pragma unroll
    for (int dn=0;dn<4;dn++){
        oA[dn][0]=0.f; oA[dn][1]=0.f; oA[dn][2]=0.f; oA[dn][3]=0.f;
        oB[dn][0]=0.f; oB[dn][1]=0.f; oB[dn][2]=0.f; oB[dn][3]=0.f;
    }

    // prologue: stage t=0 into buffer 0 (4 loads in flight)
    {
        char* b0 = (char*)smem;
        gload_lds16(ksrc,         b0 + w*2048);
        gload_lds16(ksrc + 512,   b0 + w*2048 + 1024);
        gload_lds16(vsrc,         b0 + 8192 + w*2048);
        gload_lds16(vsrc + 8*VTP, b0 + 8192 + w*2048 + 1024);
    }

    int cur = 0;
    #pragma unroll
    for (int t=0; t<4; t++){
        if (t < 3){
            char* nb = (char*)smem + (cur^1)*16384;
            gload_lds16(ksrc + (size_t)(t+1)*4096,        nb + w*2048);
            gload_lds16(ksrc + (size_t)(t+1)*4096 + 512,  nb + w*2048 + 1024);
            gload_lds16(vsrc + (t+1)*64,                  nb + 8192 + w*2048);
            gload_lds16(vsrc + (t+1)*64 + 8*VTP,          nb + 8192 + w*2048 + 1024);
            asm volatile("s_waitcnt vmcnt(4)");   // tile t landed; t+1 stays in flight
        } else {
            asm volatile("s_waitcnt vmcnt(0)");
        }
        __builtin_amdgcn_s_barrier();
        char* kl = (char*)smem + cur*16384;
        char* vl = kl + 8192;

        #pragma unroll
        for (int half=0; half<2; half++){
            u32 lo2A[2], hi2A[2], lo2B[2], hi2B[2];
            #pragma unroll
            for (int t2=0; t2<2; t2++){
                const int nt2l = half*2 + t2;       // 0..3
                const int row  = nt2l*16 + li;      // local K row
                const bf16x8 kb0 = *(const bf16x8*)(kl + row*128 + (((lg  ) ^ x7)<<4));
                const bf16x8 kb1 = *(const bf16x8*)(kl + row*128 + (((4+lg) ^ x7)<<4));
                f32x4 sA; sA[0]=0.f; sA[1]=0.f; sA[2]=0.f; sA[3]=0.f;
                f32x4 sB = sA;
                sA = __builtin_amdgcn_mfma_f32_16x16x32_bf16(kb0, qA0, sA, 0,0,0);
                sA = __builtin_amdgcn_mfma_f32_16x16x32_bf16(kb1, qA1, sA, 0,0,0);
                sB = __builtin_amdgcn_mfma_f32_16x16x32_bf16(kb0, qB0, sB, 0,0,0);
                sB = __builtin_amdgcn_mfma_f32_16x16x32_bf16(kb1, qB1, sB, 0,0,0);
                if (t == 3 && nt2l == 3){           // k = 240 + lg*4 + r >= 243
                    sA[3] = -1e30f; sB[3] = -1e30f;
                    if (lg){ sA[0]=-1e30f; sA[1]=-1e30f; sA[2]=-1e30f;
                             sB[0]=-1e30f; sB[1]=-1e30f; sB[2]=-1e30f; }
                }
                const float a0 = __expf(sA[0]);
                const float a1 = __expf(sA[1]);
                const float a2 = __expf(sA[2]);
                const float a3 = __expf(sA[3]);
                sumA += (a0+a1)+(a2+a3);
                lo2A[t2] = (u32)f2bf(a0) | ((u32)f2bf(a1) << 16);
                hi2A[t2] = (u32)f2bf(a2) | ((u32)f2bf(a3) << 16);
                const float b0 = __expf(sB[0]);
                const float b1 = __expf(sB[1]);
                const float b2 = __expf(sB[2]);
                const float b3 = __expf(sB[3]);
                sumB += (b0+b1)+(b2+b3);
                lo2B[t2] = (u32)f2bf(b0) | ((u32)f2bf(b1) << 16);
                hi2B[t2] = (u32)f2bf(b2) | ((u32)f2bf(b3) << 16);
            }
            // shuffle -> PV A-fragments: pa elem e = P[q=li][k=kt*32+lg*8+e]
            bf16x8 paA, paB;
            {
                u32 a0 = __shfl((int)lo2A[0], laneA), a1 = __shfl((int)lo2A[1], laneA);
                u32 b0 = __shfl((int)hi2A[0], laneA), b1 = __shfl((int)hi2A[1], laneA);
                u32 c0 = __shfl((int)lo2A[0], laneB), c1 = __shfl((int)lo2A[1], laneB);
                u32 d0 = __shfl((int)hi2A[0], laneB), d1 = __shfl((int)hi2A[1], laneB);
                union { u32 u[4]; bf16x8 v; } pk;
                pk.u[0] = sel ? a1 : a0;
                pk.u[1] = sel ? b1 : b0;
                pk.u[2] = sel ? c1 : c0;
                pk.u[3] = sel ? d1 : d0;
                paA = pk.v;
            }
            {
                u32 a0 = __shfl((int)lo2B[0], laneA), a1 = __shfl((int)lo2B[1], laneA);
                u32 b0 = __shfl((int)hi2B[0], laneA), b1 = __shfl((int)hi2B[1], laneA);
                u32 c0 = __shfl((int)lo2B[0], laneB), c1 = __shfl((int)lo2B[1], laneB);
                u32 d0 = __shfl((int)hi2B[0], laneB), d1 = __shfl((int)hi2B[1], laneB);
                union { u32 u[4]; bf16x8 v; } pk;
                pk.u[0] = sel ? a1 : a0;
                pk.u[1] = sel ? b1 : b0;
                pk.u[2] = sel ? c1 : c0;
                pk.u[3] = sel ? d1 : d0;
                paB = pk.v;
            }
            #pragma unroll
            for (int dn=0;dn<4;dn++){
                const int d = dn*16 + li;
                const bf16x8 vb = *(const bf16x8*)(vl + d*128 + ((((half<<2)+lg) ^ x7)<<4));
                oA[dn] = __builtin_amdgcn_mfma_f32_16x16x32_bf16(paA, vb, oA[dn], 0,0,0);
                oB[dn] = __builtin_amdgcn_mfma_f32_16x16x32_bf16(paB, vb, oB[dn], 0,0,0);
            }
        }
        __builtin_amdgcn_s_barrier();    // all reads of buf[cur] done before overwrite
        cur ^= 1;
    }

    sumA += __shfl_xor(sumA,16); sumA += __shfl_xor(sumA,32);
    sumB += __shfl_xor(sumB,16); sumB += __shfl_xor(sumB,32);
    const float invA = 1.f/sumA;
    const float invB = 1.f/sumB;
    float invrA[4], invrB[4];
    #pragma unroll
    for (int r=0;r<4;r++){
        invrA[r] = __shfl(invA, lg*4+r);
        invrB[r] = __shfl(invB, lg*4+r);
    }

    #pragma unroll
    for (int dn=0;dn<4;dn++){
        #pragma unroll
        for (int r=0;r<4;r++){
            const int qrow = qrowA + lg*4 + r;
            const size_t off = ((size_t)bj*243 + qrow)*512 + h*64 + dn*16 + li;
            float val = oA[dn][r] * invrA[r];
            if (rmw) val += bf2f(attn[off]);
            attn[off] = f2bf(val);
        }
        #pragma unroll
        for (int r=0;r<4;r++){
            const int qrow = qrowB + lg*4 + r;
            if (qrow < NSEQ){
                const size_t off = ((size_t)bj*243 + qrow)*512 + h*64 + dn*16 + li;
                float val = oB[dn][r] * invrB[r];
                if (rmw) val += bf2f(attn[off]);
                attn[off] = f2bf(val);
            }
        }
    }
}

// ---------------- projection GEMM  M=33048 x N=512 x K=512 -> bf16 fuse ----------------
__global__ __launch_bounds__(256) void k_gemm_proj(
    const u16* __restrict__ attnb, const u16* __restrict__ WprojT,
    const float* __restrict__ b_proj, u16* __restrict__ fuseb)
{
    __shared__ __align__(16) u16 smem[16384];   // 32KB: A 16KB @0, B 16KB @8192

    const int orig = blockIdx.x;
    const int xcd  = orig & 7;
    const int wg   = (xcd < 4 ? xcd*130 : 4*130 + (xcd-4)*129) + (orig >> 3);
    const int nt = wg & 3, mt = wg >> 2;

    const int tid = threadIdx.x;
    const int w = tid >> 6, lane = tid & 63;
    const int wm = w >> 1, wn = w & 1;
    const int lg = lane >> 4, li = lane & 15;
    const int x7 = li & 7;

    const int sr8  = lane >> 3;
    const int schx = (lane & 7) ^ sr8;
    const u16* gA = attnb  + (size_t)(mt*128 + w*32 + sr8)*512 + schx*8;
    const u16* gB = WprojT + (size_t)(nt*128 + w*32 + sr8)*512 + schx*8;

    f32x4 acc[4][4];
    #pragma unroll
    for (int i=0;i<4;i++)
        #pragma unroll
        for (int jj=0;jj<4;jj++){ acc[i][jj][0]=0.f; acc[i][jj][1]=0.f; acc[i][jj][2]=0.f; acc[i][jj][3]=0.f; }

    #pragma unroll
    for (int k0 = 0; k0 < 512; k0 += 64){
        __syncthreads();
        #pragma unroll
        for (int i=0;i<4;i++){
            gload_lds16(gA + i*4096 + k0, smem + (w*32 + i*8)*64);
            gload_lds16(gB + i*4096 + k0, smem + 8192 + (w*32 + i*8)*64);
        }
        __syncthreads();
        const u16* As = smem;
        const u16* Bs = smem + 8192;
        #pragma unroll
        for (int ks=0; ks<2; ks++){
            bf16x8 av[4], bv[4];
            #pragma unroll
            for (int mf=0;mf<4;mf++){
                const int R = wm*64 + mf*16 + li;
                av[mf] = *(const bf16x8*)&As[R*64 + (((ks*4+lg) ^ x7)*8)];
            }
            #pragma unroll
            for (int nf=0;nf<4;nf++){
                const int R = wn*64 + nf*16 + li;
                bv[nf] = *(const bf16x8*)&Bs[R*64 + (((ks*4+lg) ^ x7)*8)];
            }
            #pragma unroll
            for (int mf=0;mf<4;mf++)
                #pragma unroll
                for (int nf=0;nf<4;nf++)
                    acc[mf][nf] = __builtin_amdgcn_mfma_f32_16x16x32_bf16(av[mf], bv[nf], acc[mf][nf], 0, 0, 0);
        }
    }

    #pragma unroll
    for (int mf=0;mf<4;mf++)
        #pragma unroll
        for (int reg=0;reg<4;reg++){
            const int rr = mt*128 + wm*64 + mf*16 + lg*4 + reg;
            if (rr < TOK){
                #pragma unroll
                for (int nf=0;nf<4;nf++){
                    const int c = nt*128 + wn*64 + nf*16 + li;
                    fuseb[(size_t)rr*512 + c] = f2bf(acc[mf][nf][reg] + b_proj[c]);
                }
            }
        }
}

// ---------------- residual + LayerNorm (bf16 fuse, (b,j,n)->(b,n,j) permute) ------------
__global__ __launch_bounds__(256) void k_ln(
    const float* __restrict__ x, const u16* __restrict__ fuseb, float* __restrict__ out)
{
    const int w = threadIdx.x >> 6, lane = threadIdx.x & 63;
    const int o = blockIdx.x*4 + w;
    const unsigned b_  = (unsigned)o / 4131u;
    const unsigned rem = (unsigned)o % 4131u;
    const unsigned n = rem / 17u, j = rem % 17u;
    const unsigned t = (b_*17u + j)*243u + n;
    const u16*   fr = fuseb + (size_t)t*512 + lane*8;
    const float* xr = x     + (size_t)o*512 + lane*8;
    u16x8 f = *(const u16x8*)fr;
    f32x4 x0 = *(const f32x4*)xr, x1 = *(const f32x4*)(xr+4);
    float y[8];
    #pragma unroll
    for (int e=0;e<4;e++){ y[e] = x0[e]+bf2f(f[e]); y[e+4] = x1[e]+bf2f(f[e+4]); }
    float s1=0.f, s2=0.f;
    #pragma unroll
    for (int e=0;e<8;e++){ s1 += y[e]; s2 += y[e]*y[e]; }
    #pragma unroll
    for (int m=1;m<64;m<<=1){ s1 += __shfl_xor(s1,m); s2 += __shfl_xor(s2,m); }
    const float mu  = s1 * (1.f/512.f);
    const float var = s2 * (1.f/512.f) - mu*mu;
    const float rstd = rsqrtf(var + 1e-5f);
    float* orow = out + (size_t)o*512 + lane*8;
    f32x4 o0, o1;
    #pragma unroll
    for (int e=0;e<4;e++){ o0[e] = (y[e]-mu)*rstd; o1[e] = (y[e+4]-mu)*rstd; }
    *(f32x4*)orow = o0; *(f32x4*)(orow+4) = o1;
}

extern "C" void kernel_launch(void* const* d_in, const int* in_sizes, int n_in,
                              void* d_out, int out_size, void* d_ws, size_t ws_size,
                              hipStream_t stream)
{
    const float* x      = (const float*)d_in[0];
    const float* W_qkv  = (const float*)d_in[1];
    const float* b_qkv  = (const float*)d_in[2];
    const float* W_q    = (const float*)d_in[3];
    const float* b_q    = (const float*)d_in[4];
    const float* W_kv   = (const float*)d_in[5];
    const float* b_kv   = (const float*)d_in[6];
    const float* W_proj = (const float*)d_in[7];
    const float* b_proj = (const float*)d_in[8];

    // workspace layout (peak ~210.6 MB):
    //   [0, 33972224)              xbf bf16 [33048+pad][512]
    //   [33972224, 137306112)      ws3: Q [1088][243][64], K same, VT [1088][64][256]
    //   [137306112, 171278336)     attn bf16 [33048+pad][512]
    //   [171278336, 174424064)     WcatT bf16 [3072][512]
    //   [174424064, 174948352)     WprojT bf16 [512][512]
    //   [174948352, 208920576)     xmixbf bf16 [33048+pad][512]
    //   fuseb bf16 aliases ws3 (dead after attn phase 1)
    char* ws = (char*)d_ws;
    u16*   xbf    = (u16*)(ws);
    u16*   ws3    = (u16*)(ws + 33972224u);
    u16*   attn   = (u16*)(ws + 137306112u);
    u16*   WcatT  = (u16*)(ws + 171278336u);
    u16*   WprojT = (u16*)(ws + 174424064u);
    u16*   xmixbf = (u16*)(ws + 174948352u);
    u16*   fuseb  = (u16*)(ws + 33972224u);
    float* out    = (float*)d_out;

    k_cvt_xbf  <<<8262, 256, 0, stream>>>(x, xbf);
    k_mixx     <<<8262, 256, 0, stream>>>(xbf, xmixbf);
    k_cvt_wcat <<<768,  256, 0, stream>>>(W_qkv, W_q, W_kv, WcatT);
    k_cvt_wproj<<<128,  256, 0, stream>>>(W_proj, WprojT);

    // phase 0: temporal attention (A = xbf for all columns)
    k_gemm_in<<<3108, 256, 0, stream>>>(xbf, xbf, WcatT, b_qkv, b_q, b_kv, ws3, 0);
    k_attn<<<2176, 256, 0, stream>>>(ws3, ws3 + (size_t)TE, ws3 + (size_t)2*TE, attn, 0);

    // phase 1: hierarchical attention (Q from xbf; K/V from pre-mixed x -> GEMM emits
    // K_mix / V_mix directly; no post-GEMM mixers needed)
    k_gemm_in<<<3108, 256, 0, stream>>>(xbf, xmixbf, WcatT, b_qkv, b_q, b_kv, ws3, 1536);
    k_attn<<<2176, 256, 0, stream>>>(ws3, ws3 + (size_t)TE, ws3 + (size_t)2*TE, attn, 1);

    k_gemm_proj<<<1036, 256, 0, stream>>>(attn, WprojT, b_proj, fuseb);

    k_ln<<<8262, 256, 0, stream>>>(x, fuseb, out);
}